// Round 5
// baseline (3734.941 us; speedup 1.0000x reference)
//
#include <hip/hip_runtime.h>
#include <math.h>

#define HD 128
#define NBR 8
#define LSTEPS 64
#define TILE_B 32
#define HT_PAD 36
#define PART_PAD 65

// ws offsets (floats). All big tables use the half-split layout
// [..][k or cls][hid][cg][q]: lane cg reads float4 at +cg*4 (dense 1KB/instr).
#define QB_OFF   0          // [cls][hid][cg][q] = 0.5*g_emb@w_ih^T + bias   (NC*512)
#define WHH_OFF  524288     // [k][hid][cg][q]   = w_hh[(q*128+2cg+hid)][k]  (65536)
#define PP_OFF   589824     // [br][hid][cg][q]  = 0.5*w_emb@w_ih^T          (4096)
#define B2_OFF   593920     // [hid][cg][q]      = b_ih+b_hh                 (512)
// total 594432 floats = 2.38 MB

__device__ __forceinline__ float fsig(float x) {
  return __builtin_amdgcn_rcpf(1.f + __expf(-x));
}
__device__ __forceinline__ float ftanh(float x) {
  return 1.f - 2.f * __builtin_amdgcn_rcpf(1.f + __expf(2.f * x));
}

__global__ __launch_bounds__(256) void setup_kernel(
    const float* __restrict__ g_emb, const float* __restrict__ w_emb,
    const float* __restrict__ w_ih,  const float* __restrict__ w_hh,
    const float* __restrict__ b_ih,  const float* __restrict__ b_hh,
    float* __restrict__ ws, int NC)
{
  int tid = blockIdx.x * 256 + threadIdx.x;
  int qbN = NC * 512;
  if (tid < qbN) {
    int cls = tid >> 9, r = tid & 511;
    int hid = r >> 8, cg = (r >> 2) & 63, q = r & 3;
    int row = q*HD + 2*cg + hid;
    const float* er = g_emb + (size_t)cls * HD;
    const float* wr = w_ih + (size_t)row * HD;
    float s = 0.f;
    for (int k = 0; k < HD; ++k) s = fmaf(er[k], wr[k], s);
    ws[QB_OFF + tid] = 0.5f * s + b_ih[row] + b_hh[row];
    return;
  }
  int t2 = tid - qbN;
  if (t2 < 65536) {
    int k = t2 >> 9, r = t2 & 511;
    int hid = r >> 8, cg = (r >> 2) & 63, q = r & 3;
    ws[WHH_OFF + t2] = w_hh[(q*HD + 2*cg + hid)*HD + k];
    return;
  }
  int t3 = t2 - 65536;
  if (t3 < 4096) {
    int br = t3 >> 9, r = t3 & 511;
    int hid = r >> 8, cg = (r >> 2) & 63, q = r & 3;
    int row = q*HD + 2*cg + hid;
    const float* er = w_emb + br*HD;
    const float* wr = w_ih + (size_t)row * HD;
    float s = 0.f;
    for (int k = 0; k < HD; ++k) s = fmaf(er[k], wr[k], s);
    ws[PP_OFF + t3] = 0.5f * s;
    return;
  }
  int t4 = t3 - 4096;
  if (t4 < 512) {
    int hid = t4 >> 8, cg = (t4 >> 2) & 63, q = t4 & 3;
    int row = q*HD + 2*cg + hid;
    ws[B2_OFF + t4] = b_ih[row] + b_hh[row];
  }
}

// 256 threads: cg = tid&63 (hidden pair 2cg,2cg+1 x 4 quads = 8 gate-cols),
// bg = tid>>6 = wave id (8 batches each). Thread tile: 8 batches x 8 cols.
// 2 blocks/CU, 2 waves/SIMD.
__global__ __launch_bounds__(256, 2) void ctrl_kernel(
    const int* __restrict__ class_ids,
    const float* __restrict__ gumbel_u,
    const float* __restrict__ w_soft,
    const float* __restrict__ ws,
    float* __restrict__ out,
    int Btot)
{
  __shared__ float hT[2][HD * HT_PAD];       // 36864 B  double-buffered h^T [k][b]
  __shared__ float part_l[TILE_B * PART_PAD];// 8320 B
  __shared__ int   br_l[TILE_B];             // 128 B    total ~45.3 KB -> 2 blocks/CU

  const int tid = threadIdx.x;
  const int cg  = tid & 63;
  const int bg  = tid >> 6;
  const int b0  = blockIdx.x * TILE_B;
  const size_t BL = (size_t)Btot * LSTEPS;

  float bias8[8];
  {
    const float* bp = ws + B2_OFF + cg*4;
    float4 bA = *(const float4*)(bp);         // hid0: q0..3
    float4 bB = *(const float4*)(bp + 256);   // hid1: q0..3
    bias8[0]=bA.x; bias8[1]=bA.y; bias8[2]=bA.z; bias8[3]=bA.w;
    bias8[4]=bB.x; bias8[5]=bB.y; bias8[6]=bB.z; bias8[7]=bB.w;
  }

  int cidq[8];
  #pragma unroll
  for (int j = 0; j < 8; ++j)
    cidq[j] = class_ids[b0 + bg*8 + j] << 9;   // *512

  float cc[8][2];
  #pragma unroll
  for (int j = 0; j < 8; ++j) { cc[j][0] = 0.f; cc[j][1] = 0.f; }

  const float* __restrict__ wbase = ws + WHH_OFF + cg*4;

  for (int t = 0; t < LSTEPS; ++t) {
    // prefetch gumbel u for this step (overlaps GEMM)
    float4 ua = make_float4(0,0,0,0), ub = make_float4(0,0,0,0);
    if (tid < TILE_B) {
      const float* up = gumbel_u + ((size_t)t * Btot + (b0 + tid)) * NBR;
      ua = *(const float4*)up;
      ub = *(const float4*)(up + 4);
    }

    // ---- GEMM: acc[j][hid*4+q] += h[k][bj] * whh[k][col]  (skip t=0) ----
    float acc[8][8];
    #pragma unroll
    for (int j = 0; j < 8; ++j)
      #pragma unroll
      for (int g = 0; g < 8; ++g) acc[j][g] = 0.f;

    if (t > 0) {
      const float* hr = &hT[t & 1][bg*8];      // wave-uniform rows: broadcast reads
      const float* wp = wbase;
      #pragma unroll 4
      for (int k = 0; k < HD; ++k) {
        float4 w0 = *(const float4*)(wp);          // [k][hid0][cg][q] dense 1KB/wave
        float4 w1 = *(const float4*)(wp + 256);    // [k][hid1][cg][q]
        wp += 512;
        float4 h0 = *(const float4*)(hr);
        float4 h1 = *(const float4*)(hr + 4);
        hr += HT_PAD;
        #define FMAJ(j, hv) \
          acc[j][0]=fmaf(hv,w0.x,acc[j][0]); acc[j][1]=fmaf(hv,w0.y,acc[j][1]); \
          acc[j][2]=fmaf(hv,w0.z,acc[j][2]); acc[j][3]=fmaf(hv,w0.w,acc[j][3]); \
          acc[j][4]=fmaf(hv,w1.x,acc[j][4]); acc[j][5]=fmaf(hv,w1.y,acc[j][5]); \
          acc[j][6]=fmaf(hv,w1.z,acc[j][6]); acc[j][7]=fmaf(hv,w1.w,acc[j][7]);
        FMAJ(0, h0.x) FMAJ(1, h0.y) FMAJ(2, h0.z) FMAJ(3, h0.w)
        FMAJ(4, h1.x) FMAJ(5, h1.y) FMAJ(6, h1.z) FMAJ(7, h1.w)
        #undef FMAJ
      }
    }

    // ---- pointwise LSTM (registers; no barrier needed before hT write:
    //      the target buffer's last readers finished before prev step's last barrier)
    float h2a[8], h2b[8];
    #pragma unroll
    for (int j = 0; j < 8; ++j) {
      int jb = bg*8 + j;
      const float* qrow = ws + QB_OFF + cidq[j] + cg*4;
      float4 qv0 = *(const float4*)(qrow);
      float4 qv1 = *(const float4*)(qrow + 256);
      float4 pv0, pv1;
      if (t == 0) {
        pv0.x = qv0.x - bias8[0]; pv0.y = qv0.y - bias8[1];
        pv0.z = qv0.z - bias8[2]; pv0.w = qv0.w - bias8[3];
        pv1.x = qv1.x - bias8[4]; pv1.y = qv1.y - bias8[5];
        pv1.z = qv1.z - bias8[6]; pv1.w = qv1.w - bias8[7];
      } else {
        const float* prow = ws + PP_OFF + (br_l[jb] << 9) + cg*4;
        pv0 = *(const float4*)(prow);
        pv1 = *(const float4*)(prow + 256);
      }
      // hid 0
      float gi = acc[j][0] + qv0.x + pv0.x;
      float gf = acc[j][1] + qv0.y + pv0.y;
      float gc = acc[j][2] + qv0.z + pv0.z;
      float go = acc[j][3] + qv0.w + pv0.w;
      float c0 = fsig(gf)*cc[j][0] + fsig(gi)*ftanh(gc);
      cc[j][0] = c0;
      h2a[j] = fsig(go) * ftanh(c0);
      // hid 1
      gi = acc[j][4] + qv1.x + pv1.x;
      gf = acc[j][5] + qv1.y + pv1.y;
      gc = acc[j][6] + qv1.z + pv1.z;
      go = acc[j][7] + qv1.w + pv1.w;
      float c1 = fsig(gf)*cc[j][1] + fsig(gi)*ftanh(gc);
      cc[j][1] = c1;
      h2b[j] = fsig(go) * ftanh(c1);
    }
    {
      float* hw = &hT[(t & 1) ^ 1][0];
      float* d0 = &hw[(2*cg)*HT_PAD + bg*8];
      float* d1 = &hw[(2*cg + 1)*HT_PAD + bg*8];
      *(float4*)(d0)     = make_float4(h2a[0], h2a[1], h2a[2], h2a[3]);
      *(float4*)(d0 + 4) = make_float4(h2a[4], h2a[5], h2a[6], h2a[7]);
      *(float4*)(d1)     = make_float4(h2b[0], h2b[1], h2b[2], h2b[3]);
      *(float4*)(d1 + 4) = make_float4(h2b[4], h2b[5], h2b[6], h2b[7]);
    }
    __syncthreads();   // (B) new h visible

    // ---- logit partials: (lb = tid&31, ch = tid>>5), 16-k chunk each;
    //      w_soft read from global (wave-near-uniform, L1-resident)
    {
      const float* hw2 = &hT[(t & 1) ^ 1][0];
      int lb = tid & 31, ch = tid >> 5;
      const float* hcol = hw2 + (ch*16)*HT_PAD + lb;
      float part[8];
      #pragma unroll
      for (int nb = 0; nb < 8; ++nb) part[nb] = 0.f;
      #pragma unroll
      for (int ii = 0; ii < 16; ii += 4) {
        float hv0 = hcol[(ii+0)*HT_PAD];
        float hv1 = hcol[(ii+1)*HT_PAD];
        float hv2 = hcol[(ii+2)*HT_PAD];
        float hv3 = hcol[(ii+3)*HT_PAD];
        #pragma unroll
        for (int nb = 0; nb < 8; ++nb) {
          float4 wv = *(const float4*)(w_soft + nb*HD + ch*16 + ii);
          part[nb] = fmaf(hv0, wv.x, part[nb]);
          part[nb] = fmaf(hv1, wv.y, part[nb]);
          part[nb] = fmaf(hv2, wv.z, part[nb]);
          part[nb] = fmaf(hv3, wv.w, part[nb]);
        }
      }
      #pragma unroll
      for (int nb = 0; nb < 8; ++nb)
        part_l[lb*PART_PAD + nb*8 + ch] = part[nb];
    }
    __syncthreads();   // (C)

    // ---- sampling: one thread per batch row ----
    if (tid < TILE_B) {
      int lb = tid;
      float lg[8];
      #pragma unroll
      for (int nb = 0; nb < 8; ++nb) {
        const float* pr = &part_l[lb*PART_PAD + nb*8];
        float s = ((pr[0]+pr[1]) + (pr[2]+pr[3])) + ((pr[4]+pr[5]) + (pr[6]+pr[7]));
        lg[nb] = 2.5f * ftanh(s * 0.2f);
      }
      float uv[8] = {ua.x,ua.y,ua.z,ua.w,ub.x,ub.y,ub.z,ub.w};
      int br = 0; float best;
      {
        float uc = fminf(fmaxf(uv[0], 1e-8f), 0.99999999f);
        best = lg[0] - __logf(-__logf(uc));
      }
      #pragma unroll
      for (int nb = 1; nb < 8; ++nb) {
        float uc = fminf(fmaxf(uv[nb], 1e-8f), 0.99999999f);
        float y = lg[nb] - __logf(-__logf(uc));
        if (y > best) { best = y; br = nb; }
      }
      float m = lg[0];
      #pragma unroll
      for (int nb = 1; nb < 8; ++nb) m = fmaxf(m, lg[nb]);
      float se = 0.f;
      #pragma unroll
      for (int nb = 0; nb < 8; ++nb) se += __expf(lg[nb] - m);
      float lse = __logf(se);
      float lp = (lg[br] - m) - lse;
      float ent = 0.f;
      #pragma unroll
      for (int nb = 0; nb < 8; ++nb) {
        float lpi = (lg[nb] - m) - lse;
        ent -= __expf(lpi) * lpi;
      }
      size_t row = (size_t)(b0 + lb) * LSTEPS + t;
      out[row]        = (float)br;
      out[BL + row]   = lp;
      out[2*BL + row] = ent;
      out[3*BL + row] = __expf(lp);
      br_l[lb] = br;
    }
    __syncthreads();   // (E) br_l visible for next step
  }
}

extern "C" void kernel_launch(void* const* d_in, const int* in_sizes, int n_in,
                              void* d_out, int out_size, void* d_ws, size_t ws_size,
                              hipStream_t stream) {
  const int*   class_ids = (const int*)d_in[0];
  const float* gumbel_u  = (const float*)d_in[1];
  const float* g_emb     = (const float*)d_in[2];
  const float* w_emb     = (const float*)d_in[3];
  const float* w_soft    = (const float*)d_in[4];
  const float* w_ih      = (const float*)d_in[5];
  const float* w_hh      = (const float*)d_in[6];
  const float* b_ih      = (const float*)d_in[7];
  const float* b_hh      = (const float*)d_in[8];
  float* out = (float*)d_out;
  float* ws  = (float*)d_ws;
  int B  = in_sizes[0];
  int NC = in_sizes[2] / HD;

  int setup_items = NC*512 + 65536 + 4096 + 512;
  int setup_grid  = (setup_items + 255) / 256;
  hipLaunchKernelGGL(setup_kernel, dim3(setup_grid), dim3(256), 0, stream,
                     g_emb, w_emb, w_ih, w_hh, b_ih, b_hh, ws, NC);
  hipLaunchKernelGGL(ctrl_kernel, dim3(B / TILE_B), dim3(256), 0, stream,
                     class_ids, gumbel_u, w_soft, ws, out, B);
}

// Round 6
// 3537.233 us; speedup vs baseline: 1.0559x; 1.0559x over previous
//
#include <hip/hip_runtime.h>
#include <math.h>

#define HD 128
#define NBR 8
#define LSTEPS 64
#define TILE_B 32
#define HT_PAD 36
#define PART_PAD 65

// ws offsets (floats). Half-split layout [..][hid][cg][q]:
// lane cg reads float4 at +cg*4 (dense 1KB per wave instr).
#define QB_OFF   0          // [cls][hid][cg][q] = 0.5*g_emb@w_ih^T + bias   (NC*512)
#define WHH_OFF  524288     // [k][hid][cg][q]   = w_hh[(q*128+2cg+hid)][k]  (65536)
#define PP_OFF   589824     // [br][hid][cg][q]  = 0.5*w_emb@w_ih^T          (4096)
#define B2_OFF   593920     // [hid][cg][q]      = b_ih+b_hh                 (512)
// total 594432 floats = 2.38 MB

__device__ __forceinline__ float fsig(float x) {
  return __builtin_amdgcn_rcpf(1.f + __expf(-x));
}
__device__ __forceinline__ float ftanh(float x) {
  return 1.f - 2.f * __builtin_amdgcn_rcpf(1.f + __expf(2.f * x));
}

__global__ __launch_bounds__(256) void setup_kernel(
    const float* __restrict__ g_emb, const float* __restrict__ w_emb,
    const float* __restrict__ w_ih,  const float* __restrict__ w_hh,
    const float* __restrict__ b_ih,  const float* __restrict__ b_hh,
    float* __restrict__ ws, int NC)
{
  int tid = blockIdx.x * 256 + threadIdx.x;
  int qbN = NC * 512;
  if (tid < qbN) {
    int cls = tid >> 9, r = tid & 511;
    int hid = r >> 8, cg = (r >> 2) & 63, q = r & 3;
    int row = q*HD + 2*cg + hid;
    const float* er = g_emb + (size_t)cls * HD;
    const float* wr = w_ih + (size_t)row * HD;
    float s = 0.f;
    for (int k = 0; k < HD; ++k) s = fmaf(er[k], wr[k], s);
    ws[QB_OFF + tid] = 0.5f * s + b_ih[row] + b_hh[row];
    return;
  }
  int t2 = tid - qbN;
  if (t2 < 65536) {
    int k = t2 >> 9, r = t2 & 511;
    int hid = r >> 8, cg = (r >> 2) & 63, q = r & 3;
    ws[WHH_OFF + t2] = w_hh[(q*HD + 2*cg + hid)*HD + k];
    return;
  }
  int t3 = t2 - 65536;
  if (t3 < 4096) {
    int br = t3 >> 9, r = t3 & 511;
    int hid = r >> 8, cg = (r >> 2) & 63, q = r & 3;
    int row = q*HD + 2*cg + hid;
    const float* er = w_emb + br*HD;
    const float* wr = w_ih + (size_t)row * HD;
    float s = 0.f;
    for (int k = 0; k < HD; ++k) s = fmaf(er[k], wr[k], s);
    ws[PP_OFF + t3] = 0.5f * s;
    return;
  }
  int t4 = t3 - 4096;
  if (t4 < 512) {
    int hid = t4 >> 8, cg = (t4 >> 2) & 63, q = t4 & 3;
    int row = q*HD + 2*cg + hid;
    ws[B2_OFF + t4] = b_ih[row] + b_hh[row];
  }
}

// 256 threads: cg = tid&63 (hidden pair 2cg,2cg+1 x 4 quads = 8 gate-cols),
// bg = tid>>6 = wave id (8 batches each). Thread tile: 8 batches x 8 cols.
// 2 blocks/CU, 2 waves/SIMD. All per-step data: LDS + L1-resident w_hh only.
__global__ __launch_bounds__(256, 2) void ctrl_kernel(
    const int* __restrict__ class_ids,
    const float* __restrict__ gumbel_u,
    const float* __restrict__ w_soft,
    const float* __restrict__ ws,
    float* __restrict__ out,
    int Btot)
{
  __shared__ float hT[2][HD * HT_PAD];       // 36864 B  double-buffered h^T [k][b]
  __shared__ float pp_l[NBR * 512];          // 16384 B  0.5*P, [br][hid][cg][q]
  __shared__ float part_l[TILE_B * PART_PAD];// 8320 B
  __shared__ int   br_l[TILE_B];             // 128 B    total ~61.7 KB -> 2 blocks/CU

  const int tid = threadIdx.x;
  const int cg  = tid & 63;
  const int bg  = tid >> 6;
  const int b0  = blockIdx.x * TILE_B;
  const size_t BL = (size_t)Btot * LSTEPS;

  for (int i = tid; i < NBR*512; i += 256) pp_l[i] = ws[PP_OFF + i];

  float bias8[8];
  {
    const float* bp = ws + B2_OFF + cg*4;
    float4 bA = *(const float4*)(bp);         // hid0: q0..3
    float4 bB = *(const float4*)(bp + 256);   // hid1: q0..3
    bias8[0]=bA.x; bias8[1]=bA.y; bias8[2]=bA.z; bias8[3]=bA.w;
    bias8[4]=bB.x; bias8[5]=bB.y; bias8[6]=bB.z; bias8[7]=bB.w;
  }

  // Qb rows for this thread's 8 batches: read ONCE, live in registers.
  float4 qv0[8], qv1[8];
  #pragma unroll
  for (int j = 0; j < 8; ++j) {
    int cid = class_ids[b0 + bg*8 + j] << 9;
    const float* qrow = ws + QB_OFF + cid + cg*4;
    qv0[j] = *(const float4*)(qrow);
    qv1[j] = *(const float4*)(qrow + 256);
  }

  float cc[8][2];
  #pragma unroll
  for (int j = 0; j < 8; ++j) { cc[j][0] = 0.f; cc[j][1] = 0.f; }

  const float* __restrict__ wbase = ws + WHH_OFF + cg*4;

  __syncthreads();   // pp_l staged

  for (int t = 0; t < LSTEPS; ++t) {
    // prefetch gumbel u for this step (overlaps GEMM)
    float4 ua = make_float4(0,0,0,0), ub = make_float4(0,0,0,0);
    if (tid < TILE_B) {
      const float* up = gumbel_u + ((size_t)t * Btot + (b0 + tid)) * NBR;
      ua = *(const float4*)up;
      ub = *(const float4*)(up + 4);
    }

    // ---- GEMM: acc[j][hid*4+q] += h[k][bj] * whh[k][col]  (skip t=0) ----
    float acc[8][8];
    #pragma unroll
    for (int j = 0; j < 8; ++j)
      #pragma unroll
      for (int g = 0; g < 8; ++g) acc[j][g] = 0.f;

    if (t > 0) {
      const float* hr = &hT[t & 1][bg*8];      // wave-uniform rows: broadcast reads
      const float* wp = wbase;
      #pragma unroll 4
      for (int k = 0; k < HD; ++k) {
        float4 w0 = *(const float4*)(wp);          // [k][hid0][cg][q] dense 1KB/wave
        float4 w1 = *(const float4*)(wp + 256);    // [k][hid1][cg][q]
        wp += 512;
        float4 h0 = *(const float4*)(hr);
        float4 h1 = *(const float4*)(hr + 4);
        hr += HT_PAD;
        #define FMAJ(j, hv) \
          acc[j][0]=fmaf(hv,w0.x,acc[j][0]); acc[j][1]=fmaf(hv,w0.y,acc[j][1]); \
          acc[j][2]=fmaf(hv,w0.z,acc[j][2]); acc[j][3]=fmaf(hv,w0.w,acc[j][3]); \
          acc[j][4]=fmaf(hv,w1.x,acc[j][4]); acc[j][5]=fmaf(hv,w1.y,acc[j][5]); \
          acc[j][6]=fmaf(hv,w1.z,acc[j][6]); acc[j][7]=fmaf(hv,w1.w,acc[j][7]);
        FMAJ(0, h0.x) FMAJ(1, h0.y) FMAJ(2, h0.z) FMAJ(3, h0.w)
        FMAJ(4, h1.x) FMAJ(5, h1.y) FMAJ(6, h1.z) FMAJ(7, h1.w)
        #undef FMAJ
      }
    }

    // ---- pointwise LSTM (registers; double-buffered hT => no pre-write barrier:
    //      last readers of the target buffer finished before prev step's barrier E)
    float h2a[8], h2b[8];
    #pragma unroll
    for (int j = 0; j < 8; ++j) {
      float gi, gf, gc, go;
      if (t == 0) {
        gi = 2.f*qv0[j].x - bias8[0];
        gf = 2.f*qv0[j].y - bias8[1];
        gc = 2.f*qv0[j].z - bias8[2];
        go = 2.f*qv0[j].w - bias8[3];
      } else {
        const float* prow = &pp_l[(br_l[bg*8 + j] << 9) + cg*4];
        float4 pv0 = *(const float4*)(prow);
        gi = acc[j][0] + qv0[j].x + pv0.x;
        gf = acc[j][1] + qv0[j].y + pv0.y;
        gc = acc[j][2] + qv0[j].z + pv0.z;
        go = acc[j][3] + qv0[j].w + pv0.w;
      }
      float c0 = fsig(gf)*cc[j][0] + fsig(gi)*ftanh(gc);
      cc[j][0] = c0;
      h2a[j] = fsig(go) * ftanh(c0);

      if (t == 0) {
        gi = 2.f*qv1[j].x - bias8[4];
        gf = 2.f*qv1[j].y - bias8[5];
        gc = 2.f*qv1[j].z - bias8[6];
        go = 2.f*qv1[j].w - bias8[7];
      } else {
        const float* prow = &pp_l[(br_l[bg*8 + j] << 9) + cg*4 + 256];
        float4 pv1 = *(const float4*)(prow);
        gi = acc[j][4] + qv1[j].x + pv1.x;
        gf = acc[j][5] + qv1[j].y + pv1.y;
        gc = acc[j][6] + qv1[j].z + pv1.z;
        go = acc[j][7] + qv1[j].w + pv1.w;
      }
      float c1 = fsig(gf)*cc[j][1] + fsig(gi)*ftanh(gc);
      cc[j][1] = c1;
      h2b[j] = fsig(go) * ftanh(c1);
    }
    {
      float* hw = &hT[(t & 1) ^ 1][0];
      float* d0 = &hw[(2*cg)*HT_PAD + bg*8];
      float* d1 = &hw[(2*cg + 1)*HT_PAD + bg*8];
      *(float4*)(d0)     = make_float4(h2a[0], h2a[1], h2a[2], h2a[3]);
      *(float4*)(d0 + 4) = make_float4(h2a[4], h2a[5], h2a[6], h2a[7]);
      *(float4*)(d1)     = make_float4(h2b[0], h2b[1], h2b[2], h2b[3]);
      *(float4*)(d1 + 4) = make_float4(h2b[4], h2b[5], h2b[6], h2b[7]);
    }
    __syncthreads();   // (B) new h visible

    // ---- logit partials: (lb = tid&31, ch = tid>>5), 16-k chunk each;
    //      w_soft from global (2 distinct lines/wave instr, L1-resident)
    {
      const float* hw2 = &hT[(t & 1) ^ 1][0];
      int lb = tid & 31, ch = tid >> 5;
      const float* hcol = hw2 + (ch*16)*HT_PAD + lb;
      float part[8];
      #pragma unroll
      for (int nb = 0; nb < 8; ++nb) part[nb] = 0.f;
      #pragma unroll
      for (int ii = 0; ii < 16; ii += 4) {
        float hv0 = hcol[(ii+0)*HT_PAD];
        float hv1 = hcol[(ii+1)*HT_PAD];
        float hv2 = hcol[(ii+2)*HT_PAD];
        float hv3 = hcol[(ii+3)*HT_PAD];
        #pragma unroll
        for (int nb = 0; nb < 8; ++nb) {
          float4 wv = *(const float4*)(w_soft + nb*HD + ch*16 + ii);
          part[nb] = fmaf(hv0, wv.x, part[nb]);
          part[nb] = fmaf(hv1, wv.y, part[nb]);
          part[nb] = fmaf(hv2, wv.z, part[nb]);
          part[nb] = fmaf(hv3, wv.w, part[nb]);
        }
      }
      #pragma unroll
      for (int nb = 0; nb < 8; ++nb)
        part_l[lb*PART_PAD + nb*8 + ch] = part[nb];
    }
    __syncthreads();   // (C)

    // ---- sampling: one thread per batch row ----
    if (tid < TILE_B) {
      int lb = tid;
      float lg[8];
      #pragma unroll
      for (int nb = 0; nb < 8; ++nb) {
        const float* pr = &part_l[lb*PART_PAD + nb*8];
        float s = ((pr[0]+pr[1]) + (pr[2]+pr[3])) + ((pr[4]+pr[5]) + (pr[6]+pr[7]));
        lg[nb] = 2.5f * ftanh(s * 0.2f);
      }
      float uv[8] = {ua.x,ua.y,ua.z,ua.w,ub.x,ub.y,ub.z,ub.w};
      int br = 0; float best;
      {
        float uc = fminf(fmaxf(uv[0], 1e-8f), 0.99999999f);
        best = lg[0] - __logf(-__logf(uc));
      }
      #pragma unroll
      for (int nb = 1; nb < 8; ++nb) {
        float uc = fminf(fmaxf(uv[nb], 1e-8f), 0.99999999f);
        float y = lg[nb] - __logf(-__logf(uc));
        if (y > best) { best = y; br = nb; }
      }
      float m = lg[0];
      #pragma unroll
      for (int nb = 1; nb < 8; ++nb) m = fmaxf(m, lg[nb]);
      float se = 0.f;
      #pragma unroll
      for (int nb = 0; nb < 8; ++nb) se += __expf(lg[nb] - m);
      float lse = __logf(se);
      float lp = (lg[br] - m) - lse;
      float ent = 0.f;
      #pragma unroll
      for (int nb = 0; nb < 8; ++nb) {
        float lpi = (lg[nb] - m) - lse;
        ent -= __expf(lpi) * lpi;
      }
      size_t row = (size_t)(b0 + lb) * LSTEPS + t;
      out[row]        = (float)br;
      out[BL + row]   = lp;
      out[2*BL + row] = ent;
      out[3*BL + row] = __expf(lp);
      br_l[lb] = br;
    }
    __syncthreads();   // (E) br_l visible for next step
  }
}

extern "C" void kernel_launch(void* const* d_in, const int* in_sizes, int n_in,
                              void* d_out, int out_size, void* d_ws, size_t ws_size,
                              hipStream_t stream) {
  const int*   class_ids = (const int*)d_in[0];
  const float* gumbel_u  = (const float*)d_in[1];
  const float* g_emb     = (const float*)d_in[2];
  const float* w_emb     = (const float*)d_in[3];
  const float* w_soft    = (const float*)d_in[4];
  const float* w_ih      = (const float*)d_in[5];
  const float* w_hh      = (const float*)d_in[6];
  const float* b_ih      = (const float*)d_in[7];
  const float* b_hh      = (const float*)d_in[8];
  float* out = (float*)d_out;
  float* ws  = (float*)d_ws;
  int B  = in_sizes[0];
  int NC = in_sizes[2] / HD;

  int setup_items = NC*512 + 65536 + 4096 + 512;
  int setup_grid  = (setup_items + 255) / 256;
  hipLaunchKernelGGL(setup_kernel, dim3(setup_grid), dim3(256), 0, stream,
                     g_emb, w_emb, w_ih, w_hh, b_ih, b_hh, ws, NC);
  hipLaunchKernelGGL(ctrl_kernel, dim3(B / TILE_B), dim3(256), 0, stream,
                     class_ids, gumbel_u, w_soft, ws, out, B);
}